// Round 6
// baseline (365.522 us; speedup 1.0000x reference)
//
#include <hip/hip_runtime.h>
#include <hip/hip_bf16.h>
#include <cmath>
#include <cstdint>

typedef __attribute__((ext_vector_type(8))) short short8;
typedef __attribute__((ext_vector_type(4))) float floatx4;
typedef __attribute__((ext_vector_type(4))) unsigned int uintx4;

typedef const __attribute__((address_space(1))) unsigned int* gas_p;
typedef __attribute__((address_space(3))) unsigned int* las_p;

#define LOG2E 1.4426950408889634f

__device__ inline unsigned short f2bf(float f) {
  unsigned int u = __builtin_bit_cast(unsigned int, f);
  unsigned int r = (u + 0x7FFFu + ((u >> 16) & 1u)) >> 16;
  return (unsigned short)r;
}
__device__ inline float bf2f(unsigned short h) {
  unsigned int u = ((unsigned int)h) << 16;
  return __builtin_bit_cast(float, u);
}

// ---------------- transpose + convert + scale: fp32 [K][N] -> bf16 [N][K] ----------------
__global__ void k_transpose_w(const float* __restrict__ in, unsigned short* __restrict__ out,
                              int K, int N, float scl) {
  __shared__ float t[32][33];
  int n0 = blockIdx.x * 32, k0 = blockIdx.y * 32;
  int tx = threadIdx.x & 31, ty = threadIdx.x >> 5; // 256 threads: ty 0..7
  #pragma unroll
  for (int r = ty; r < 32; r += 8)
    t[r][tx] = in[(long)(k0 + r) * N + n0 + tx];
  __syncthreads();
  #pragma unroll
  for (int r = ty; r < 32; r += 8)
    out[(long)(n0 + r) * K + k0 + tx] = f2bf(t[tx][r] * scl);
}

// ---------------- small fp32 GEMM: out[d][0..3] = W[d,:] @ Ws (Kw x 4) ----------------
__global__ void k_wproj(const float* __restrict__ W, const float* __restrict__ Ws,
                        float* __restrict__ out, int Kw) {
  int d = blockIdx.x;
  float a0 = 0, a1 = 0, a2 = 0, a3 = 0;
  for (int j = threadIdx.x; j < Kw; j += 256) {
    float w = W[(long)d * Kw + j];
    float4 g = reinterpret_cast<const float4*>(Ws)[j];
    a0 += w * g.x; a1 += w * g.y; a2 += w * g.z; a3 += w * g.w;
  }
  #pragma unroll
  for (int off = 1; off < 64; off <<= 1) {
    a0 += __shfl_xor(a0, off, 64); a1 += __shfl_xor(a1, off, 64);
    a2 += __shfl_xor(a2, off, 64); a3 += __shfl_xor(a3, off, 64);
  }
  __shared__ float red[4][4];
  if ((threadIdx.x & 63) == 0) {
    int wv = threadIdx.x >> 6;
    red[wv][0] = a0; red[wv][1] = a1; red[wv][2] = a2; red[wv][3] = a3;
  }
  __syncthreads();
  if (threadIdx.x < 4) {
    int nn = threadIdx.x;
    out[d * 4 + nn] = red[0][nn] + red[1][nn] + red[2][nn] + red[3][nn];
  }
}

// ---------------- bias (fp32), pre-masked + log2e-scaled; ALSO emits hs row as bf16 ----------------
// R12: fused the old k_f32_to_bf16 pass into this kernel (it already reads every hs row) —
// saves a full 50 MB read+write pass + one launch.
__global__ void k_bias(const float* __restrict__ hs, const float* __restrict__ Wqg,
                       const float* __restrict__ Wvd, float* __restrict__ bias,
                       unsigned short* __restrict__ hsb) {
  int row = blockIdx.x;           // b*2048 + s
  int b = row >> 11, s = row & 2047;
  float g0 = 0, g1 = 0, g2 = 0, g3 = 0, d0 = 0, d1 = 0, d2 = 0, d3 = 0;
  const float* h = hs + (long)row * 2048;
  for (int j = threadIdx.x; j < 2048; j += 256) {
    float x = h[j];
    float4 a = reinterpret_cast<const float4*>(Wqg)[j];
    float4 c = reinterpret_cast<const float4*>(Wvd)[j];
    g0 += x * a.x; g1 += x * a.y; g2 += x * a.z; g3 += x * a.w;
    d0 += x * c.x; d1 += x * c.y; d2 += x * c.z; d3 += x * c.w;
  }
  // bf16 conversion of this row (vectorized, coalesced): 2 iterations of float4 -> uint2
  {
    const float4* h4 = reinterpret_cast<const float4*>(h);
    uint2* o2p = reinterpret_cast<uint2*>(hsb + (long)row * 2048);
    #pragma unroll
    for (int it = 0; it < 2; it++) {
      int j4 = it * 256 + threadIdx.x;
      float4 v = h4[j4];
      uint2 o2;
      o2.x = (unsigned)f2bf(v.x) | ((unsigned)f2bf(v.y) << 16);
      o2.y = (unsigned)f2bf(v.z) | ((unsigned)f2bf(v.w) << 16);
      o2p[j4] = o2;
    }
  }
  #pragma unroll
  for (int off = 1; off < 64; off <<= 1) {
    g0 += __shfl_xor(g0, off, 64); g1 += __shfl_xor(g1, off, 64);
    g2 += __shfl_xor(g2, off, 64); g3 += __shfl_xor(g3, off, 64);
    d0 += __shfl_xor(d0, off, 64); d1 += __shfl_xor(d1, off, 64);
    d2 += __shfl_xor(d2, off, 64); d3 += __shfl_xor(d3, off, 64);
  }
  __shared__ float red[4][8];
  if ((threadIdx.x & 63) == 0) {
    int wv = threadIdx.x >> 6;
    red[wv][0] = g0; red[wv][1] = g1; red[wv][2] = g2; red[wv][3] = g3;
    red[wv][4] = d0; red[wv][5] = d1; red[wv][6] = d2; red[wv][7] = d3;
  }
  __syncthreads();
  if (threadIdx.x < 4) {
    int nn = threadIdx.x;
    float gg = red[0][nn] + red[1][nn] + red[2][nn] + red[3][nn];
    float dd = red[0][4 + nn] + red[1][4 + nn] + red[2][4 + nn] + red[3][4 + nn];
    float sig = 1.0f / (1.0f + __expf(-gg));
    float v = sig * dd;
    bias[(b * 4 + nn) * 2048 + s] = (v > 0.0f) ? v * LOG2E : -INFINITY;
  }
}

// ---------------- key compaction scan: per (b,n) sorted allowed-key list ----------------
__global__ void k_scan(const float* __restrict__ biasb, int* __restrict__ idx,
                       float* __restrict__ biasc, int* __restrict__ kendArr) {
  const int bn = blockIdx.x;        // 8
  const int t = threadIdx.x;        // 256, each handles 8 consecutive positions
  const float* br = biasb + bn * 2048;
  float v[8]; int pred[8]; int c = 0;
  #pragma unroll
  for (int i = 0; i < 8; i++) {
    v[i] = br[t * 8 + i];
    pred[i] = (v[i] > -1e30f) ? 1 : 0;
    c += pred[i];
  }
  __shared__ int cnts[256];
  __shared__ int offs[257];
  cnts[t] = c;
  __syncthreads();
  if (t == 0) {
    int acc = 0;
    for (int i = 0; i < 256; i++) { offs[i] = acc; acc += cnts[i]; }
    offs[256] = acc;
  }
  __syncthreads();
  int off = offs[t];
  #pragma unroll
  for (int i = 0; i < 8; i++) {
    if (pred[i]) {
      idx[bn * 2048 + off] = t * 8 + i;
      biasc[bn * 2048 + off] = v[i];
      off++;
    }
  }
  const int cnt = offs[256];
  for (int j = cnt + t; j < 2048; j += 256) {
    idx[bn * 2048 + j] = 0x7FFFFFFF;
    biasc[bn * 2048 + j] = -INFINITY;
  }
  if (t == 0) {
    for (int qt = 0; qt < 32; qt++) {
      int pc = offs[(qt + 1) * 8];
      kendArr[bn * 32 + qt] = (pc + 63) & ~63;
    }
  }
}

// ---------------- gather compacted K rows ----------------
__global__ void k_gatherk(const unsigned short* __restrict__ qkv, const int* __restrict__ idx,
                          unsigned short* __restrict__ Kc) {
  const int bn = blockIdx.y, b = bn >> 2, n = bn & 3;
  const int j = blockIdx.x * 16 + (threadIdx.x >> 4);
  const int seg = threadIdx.x & 15;
  const int s = idx[bn * 2048 + j];
  uintx4 val = {0u, 0u, 0u, 0u};
  if (s < 2048)
    val = *reinterpret_cast<const uintx4*>(qkv + ((long)(b * 2048 + s)) * 3072 + 2048 + n * 128 + seg * 8);
  *reinterpret_cast<uintx4*>(Kc + ((long)bn * 2048 + j) * 128 + seg * 8) = val;
}

// ---------------- gather + transpose compacted V: vTc[bn][hd][j] ----------------
__global__ void k_gathervt(const unsigned short* __restrict__ qkv, const int* __restrict__ idx,
                           unsigned short* __restrict__ vTc) {
  __shared__ unsigned short t[32][33];
  const int bn = blockIdx.z, b = bn >> 2, n = bn & 3;
  const int c0 = blockIdx.x * 32, j0 = blockIdx.y * 32;
  const int tx = threadIdx.x & 31, ty = threadIdx.x >> 5;
  #pragma unroll
  for (int r = ty; r < 32; r += 8) {
    const int s = idx[bn * 2048 + j0 + r];
    t[r][tx] = (s < 2048)
        ? qkv[((long)(b * 2048 + s)) * 3072 + 2560 + n * 128 + c0 + tx]
        : (unsigned short)0;
  }
  __syncthreads();
  #pragma unroll
  for (int r = ty; r < 32; r += 8)
    vTc[((long)bn * 128 + c0 + r) * 2048 + j0 + tx] = t[tx][r];
}

// ---------------- direct vmean from qkv V region (replaces transpose_v + vmean2) ----------------
// R12: full vT was only consumed by vmean after compaction; one 8.4 MB column-sum pass.
__global__ void k_vmeand(const unsigned short* __restrict__ qkv, float* __restrict__ vmean) {
  const int bn = blockIdx.x, b = bn >> 2, n = bn & 3;
  const int t = threadIdx.x;
  const int cg = (t & 15) * 8;      // col group base (0..120)
  const int rg = t >> 4;            // row phase 0..15
  const unsigned short* base = qkv + (long)(b * 2048) * 3072 + 2560 + n * 128 + cg;
  float s[8] = {0.f, 0.f, 0.f, 0.f, 0.f, 0.f, 0.f, 0.f};
  for (int r = rg; r < 2048; r += 16) {
    uintx4 v = *reinterpret_cast<const uintx4*>(base + (long)r * 3072);
    #pragma unroll
    for (int i = 0; i < 4; i++) {
      unsigned u = v[i];
      s[2 * i]     += bf2f((unsigned short)(u & 0xffff));
      s[2 * i + 1] += bf2f((unsigned short)(u >> 16));
    }
  }
  __shared__ float red[256][8];
  #pragma unroll
  for (int i = 0; i < 8; i++) red[t][i] = s[i];
  __syncthreads();
  if (t < 128) {
    const int colg = t >> 3, i = t & 7;
    float acc = 0.f;
    #pragma unroll
    for (int gg = 0; gg < 16; gg++) acc += red[gg * 16 + colg][i];
    vmean[bn * 128 + t] = acc * (1.0f / 2048.0f);
  }
}

// ---------------- bf16 MFMA GEMM: C[M,N] = A[M,K] @ Bt[N,K]^T ----------------
template <int WRITE_BF16>
__global__ __launch_bounds__(256, 2) void k_gemm_bt(
    const unsigned short* __restrict__ A, const unsigned short* __restrict__ Bt,
    void* __restrict__ Cout, int M, int N, int K) {
  __shared__ __align__(16) unsigned short As[128 * 32];
  __shared__ __align__(16) unsigned short Bs[128 * 32];
  const int tid = threadIdx.x;
  const int lane = tid & 63, wave = tid >> 6;
  const int quad = lane >> 4, l16 = lane & 15;
  const long bm = (long)blockIdx.y * 128, bn = (long)blockIdx.x * 128;
  const int wm = (wave >> 1) * 64, wn = (wave & 1) * 64;

  const floatx4 fz = {0.f, 0.f, 0.f, 0.f};
  floatx4 acc[4][4];
  #pragma unroll
  for (int i = 0; i < 4; i++)
    #pragma unroll
    for (int j = 0; j < 4; j++) acc[i][j] = fz;

  const int r0 = tid >> 2, c0 = (tid & 3) * 8;
  const unsigned short* Ag = A + (bm + r0) * K + c0;
  const unsigned short* Bg = Bt + (bn + r0) * K + c0;
  unsigned short* AsW0 = As + (wave * 16) * 32;
  unsigned short* AsW1 = As + (wave * 16 + 64) * 32;
  unsigned short* BsW0 = Bs + (wave * 16) * 32;
  unsigned short* BsW1 = Bs + (wave * 16 + 64) * 32;

  for (int kt = 0; kt < K; kt += 32) {
    __syncthreads();
    __builtin_amdgcn_global_load_lds((gas_p)(const void*)(Ag + kt),
                                     (las_p)(void*)AsW0, 16, 0, 0);
    __builtin_amdgcn_global_load_lds((gas_p)(const void*)(Ag + (long)64 * K + kt),
                                     (las_p)(void*)AsW1, 16, 0, 0);
    __builtin_amdgcn_global_load_lds((gas_p)(const void*)(Bg + kt),
                                     (las_p)(void*)BsW0, 16, 0, 0);
    __builtin_amdgcn_global_load_lds((gas_p)(const void*)(Bg + (long)64 * K + kt),
                                     (las_p)(void*)BsW1, 16, 0, 0);
    __syncthreads();
    short8 af[4], bf[4];
    #pragma unroll
    for (int i = 0; i < 4; i++)
      af[i] = *reinterpret_cast<const short8*>(&As[(wm + i * 16 + l16) * 32 + quad * 8]);
    #pragma unroll
    for (int j = 0; j < 4; j++)
      bf[j] = *reinterpret_cast<const short8*>(&Bs[(wn + j * 16 + l16) * 32 + quad * 8]);
    #pragma unroll
    for (int i = 0; i < 4; i++)
      #pragma unroll
      for (int j = 0; j < 4; j++)
        acc[i][j] = __builtin_amdgcn_mfma_f32_16x16x32_bf16(af[i], bf[j], acc[i][j], 0, 0, 0);
  }
  #pragma unroll
  for (int i = 0; i < 4; i++)
    #pragma unroll
    for (int j = 0; j < 4; j++)
      #pragma unroll
      for (int r = 0; r < 4; r++) {
        const long row = bm + wm + i * 16 + quad * 4 + r;
        const long col = bn + wn + j * 16 + l16;
        const float v = acc[i][j][r];
        if (WRITE_BF16)
          ((unsigned short*)Cout)[row * N + col] = f2bf(v);
        else
          ((float*)Cout)[row * N + col] = v;
      }
}

// ---------------- flash attention over COMPACTED keys (dynamic mask exploited) ----------------
// R11 structure unchanged (harness-verified): K/V/bias pre-compacted to keys with bias > 0,
// causal test via original-position LDS tile Is, kend ~halved.
// grid 1024 = qt(32, LPT) x b(2) x n(4) x g(4); 4 waves; wave owns 16 q rows.
// LDS: Ks 64x144 + Vs 128x72 + Ps 4x16x72 + Is 64 ints = 46,336 B -> 3 blocks/CU.
__global__ __launch_bounds__(256, 3) void k_attn(
    const unsigned short* __restrict__ qkv,   // [4096][3072] (q | k | v); q pre-scaled
    const unsigned short* __restrict__ Kc,    // [8][2048][128] compacted K (pads zero)
    const float* __restrict__ biasc,          // [8][2048] compacted bias (pads -INF)
    const unsigned short* __restrict__ vTc,   // [8][128][2048] compacted V^T (pads zero)
    const int* __restrict__ idxArr,           // [8][2048] original positions (pads INT_MAX)
    const int* __restrict__ kendArr,          // [8][32]
    const float* __restrict__ vmean,          // [1024]
    unsigned short* __restrict__ o)           // [4096][2048]
{
  int idx = blockIdx.x;
  const int g = idx & 3;
  const int n = (idx >> 2) & 3;
  const int b = (idx >> 4) & 1;
  const int qt = 31 - (idx >> 5);            // 64-row q tiles, big blocks dispatch first (LPT)
  const int tid = threadIdx.x, lane = tid & 63, wave = tid >> 6;
  const int quad = lane >> 4, l16 = lane & 15;
  const int q0 = qt * 64 + wave * 16;
  const int bn = b * 4 + n;

  __shared__ __align__(16) unsigned short Ks[64 * 144];
  __shared__ __align__(16) unsigned short Vs[128 * 72];
  __shared__ __align__(16) unsigned short Ps[4 * 16 * 72];
  __shared__ __align__(16) int Is[64];
  unsigned short* Psw = Ps + wave * 1152;    // 16 x 72 [q][key], per-wave private

  // Q fragments (B-operand for K@Q^T): row=q0+l16, k=ks*32+quad*8..+8
  short8 qf[4];
  {
    const unsigned short* qp = qkv + (long)(b * 2048) * 3072 + (n * 4 + g) * 128;
    #pragma unroll
    for (int ks = 0; ks < 4; ks++)
      qf[ks] = *reinterpret_cast<const short8*>(
          qp + (long)(q0 + l16) * 3072 + ks * 32 + quad * 8);
  }

  const floatx4 fz = {0.f, 0.f, 0.f, 0.f};
  floatx4 oacc[8];
  #pragma unroll
  for (int j = 0; j < 8; j++) oacc[j] = fz;
  float mrow = -INFINITY, lrow = 0.0f;       // per-lane: q = q0 + l16 (replicated across quads)

  const float* biasrow = biasc + bn * 2048;
  const unsigned short* kbase = Kc + (long)bn * 2048 * 128;
  const unsigned short* vbase = vTc + (long)bn * 128 * 2048;
  const int* idxp = idxArr + bn * 2048;
  const int kend = kendArr[bn * 32 + qt];
  const int kk_ = tid >> 4, hdo_ = (tid & 15) * 8;   // K staging coords (row += 16/pass)
  const int hd_ = tid >> 3, ko_ = (tid & 7) * 8;     // V staging coords (row += 32/pass)

  uintx4 kreg[4], vreg[4];
  float4 breg[4];
  int ireg;
  // prologue: load tile 0
  {
    #pragma unroll
    for (int it = 0; it < 4; it++)
      kreg[it] = *reinterpret_cast<const uintx4*>(kbase + (long)(kk_ + it * 16) * 128 + hdo_);
    #pragma unroll
    for (int it = 0; it < 4; it++)
      vreg[it] = *reinterpret_cast<const uintx4*>(vbase + (long)(hd_ + it * 32) * 2048 + ko_);
    #pragma unroll
    for (int kt = 0; kt < 4; kt++)
      breg[kt] = *reinterpret_cast<const float4*>(biasrow + kt * 16 + quad * 4);
    ireg = idxp[tid & 63];
  }

  for (int k0 = 0; k0 < kend; k0 += 64) {
    __syncthreads();  // (A) all waves done with LDS reads of previous tile
    // commit prefetched tile to LDS
    #pragma unroll
    for (int it = 0; it < 4; it++)
      *reinterpret_cast<uintx4*>(&Ks[(kk_ + it * 16) * 144 + hdo_]) = kreg[it];
    #pragma unroll
    for (int it = 0; it < 4; it++)
      *reinterpret_cast<uintx4*>(&Vs[(hd_ + it * 32) * 72 + ko_]) = vreg[it];
    if (tid < 64) Is[tid] = ireg;
    float4 bcur[4];
    #pragma unroll
    for (int kt = 0; kt < 4; kt++) bcur[kt] = breg[kt];

    // issue next tile's loads (land during this tile's compute)
    if (k0 + 64 < kend) {
      const unsigned short* kp = kbase + (long)(k0 + 64) * 128;
      const unsigned short* vp = vbase + (k0 + 64);
      #pragma unroll
      for (int it = 0; it < 4; it++)
        kreg[it] = *reinterpret_cast<const uintx4*>(kp + (long)(kk_ + it * 16) * 128 + hdo_);
      #pragma unroll
      for (int it = 0; it < 4; it++)
        vreg[it] = *reinterpret_cast<const uintx4*>(vp + (long)(hd_ + it * 32) * 2048 + ko_);
      #pragma unroll
      for (int kt = 0; kt < 4; kt++)
        breg[kt] = *reinterpret_cast<const float4*>(biasrow + (k0 + 64) + kt * 16 + quad * 4);
      ireg = idxp[k0 + 64 + (tid & 63)];
    }
    __syncthreads();  // (B) staged tile visible

    const int ifirst = Is[0];
    const bool active = (ifirst <= q0 + 15);
    if (active) {
      // S^T tile: sacc[kt] rows = compacted keys k0+kt*16+quad*4+r, col = q0+l16. C-init = bias.
      floatx4 sacc[4];
      #pragma unroll
      for (int kt = 0; kt < 4; kt++)
        sacc[kt] = (floatx4){bcur[kt].x, bcur[kt].y, bcur[kt].z, bcur[kt].w};
      __builtin_amdgcn_s_setprio(1);
      #pragma unroll
      for (int ks = 0; ks < 4; ks++) {
        short8 kf[4];
        #pragma unroll
        for (int kt = 0; kt < 4; kt++)
          kf[kt] = *reinterpret_cast<const short8*>(&Ks[(kt * 16 + l16) * 144 + ks * 32 + quad * 8]);
        #pragma unroll
        for (int kt = 0; kt < 4; kt++)
          sacc[kt] = __builtin_amdgcn_mfma_f32_16x16x32_bf16(kf[kt], qf[ks], sacc[kt], 0, 0, 0);
      }
      __builtin_amdgcn_s_setprio(0);

      // softmax (register-only): causal mask via original positions, in-lane max/sum + 2 shfls
      const int ilast = Is[63];
      const bool full = (ilast <= q0);
      if (!full) {
        const int qme = q0 + l16;
        #pragma unroll
        for (int kt = 0; kt < 4; kt++) {
          const int4 iq = *reinterpret_cast<const int4*>(&Is[kt * 16 + quad * 4]);
          if (iq.x > qme) sacc[kt][0] = -INFINITY;
          if (iq.y > qme) sacc[kt][1] = -INFINITY;
          if (iq.z > qme) sacc[kt][2] = -INFINITY;
          if (iq.w > qme) sacc[kt][3] = -INFINITY;
        }
      }
      float mx = -INFINITY;
      #pragma unroll
      for (int kt = 0; kt < 4; kt++)
        #pragma unroll
        for (int r = 0; r < 4; r++) mx = fmaxf(mx, sacc[kt][r]);
      mx = fmaxf(mx, __shfl_xor(mx, 16, 64));
      mx = fmaxf(mx, __shfl_xor(mx, 32, 64));
      const float mn = fmaxf(mrow, mx);
      const float mnc = fmaxf(mn, -1e38f);
      const float alpha = __builtin_amdgcn_exp2f(mrow - mnc);
      float rs = 0.0f;
      unsigned pk[4][2];
      #pragma unroll
      for (int kt = 0; kt < 4; kt++) {
        #pragma unroll
        for (int r = 0; r < 4; r++) {
          float p = __builtin_amdgcn_exp2f(sacc[kt][r] - mnc);
          sacc[kt][r] = p;
          rs += p;
        }
        #pragma unroll
        for (int r2 = 0; r2 < 2; r2++)
          pk[kt][r2] = (unsigned)f2bf(sacc[kt][2 * r2]) | ((unsigned)f2bf(sacc[kt][2 * r2 + 1]) << 16);
      }
      rs += __shfl_xor(rs, 16, 64);
      rs += __shfl_xor(rs, 32, 64);
      mrow = mn;
      lrow = lrow * alpha + rs;

      // rescale O: alpha in q=l16 space -> oacc q=quad*4+r space via bpermute
      float al[4];
      #pragma unroll
      for (int r = 0; r < 4; r++) al[r] = __shfl(alpha, quad * 4 + r, 64);
      #pragma unroll
      for (int j = 0; j < 8; j++)
        #pragma unroll
        for (int r = 0; r < 4; r++) oacc[j][r] *= al[r];

      // store packed P to Psw[q=l16][key] (own buffer, wave-private: no barrier)
      unsigned* Pd = reinterpret_cast<unsigned*>(Psw);
      #pragma unroll
      for (int kt = 0; kt < 4; kt++)
        #pragma unroll
        for (int r2 = 0; r2 < 2; r2++)
          Pd[l16 * 36 + kt * 8 + quad * 2 + r2] = pk[kt][r2];

      // O += P @ V  (A = P [q][key], B = V^T [key][hd])
      __builtin_amdgcn_s_setprio(1);
      #pragma unroll
      for (int ks2 = 0; ks2 < 2; ks2++) {
        short8 pf = *reinterpret_cast<const short8*>(&Psw[l16 * 72 + ks2 * 32 + quad * 8]);
        #pragma unroll
        for (int j = 0; j < 8; j++) {
          short8 vf = *reinterpret_cast<const short8*>(&Vs[(j * 16 + l16) * 72 + ks2 * 32 + quad * 8]);
          oacc[j] = __builtin_amdgcn_mfma_f32_16x16x32_bf16(pf, vf, oacc[j], 0, 0, 0);
        }
      }
      __builtin_amdgcn_s_setprio(0);
    }
  }

  // epilogue: oacc rows q=q0+quad*4+r; l lives in q=l16 space -> bpermute
  const long obase = (long)(b * 2048) * 2048 + (n * 4 + g) * 128;
  #pragma unroll
  for (int r = 0; r < 4; r++) {
    const int qrow = q0 + quad * 4 + r;
    const float l = __shfl(lrow, quad * 4 + r, 64);
    const float inv = (l > 0.0f) ? 1.0f / l : 0.0f;
    #pragma unroll
    for (int j = 0; j < 8; j++) {
      const int hd = j * 16 + l16;
      float v = oacc[j][r] * inv;
      if (l <= 0.0f) v = vmean[(b * 4 + n) * 128 + hd];  // empty row: uniform softmax over ALL keys
      o[obase + (long)qrow * 2048 + hd] = f2bf(v);
    }
  }
}

extern "C" void kernel_launch(void* const* d_in, const int* in_sizes, int n_in,
                              void* d_out, int out_size, void* d_ws, size_t ws_size,
                              hipStream_t stream) {
  const float* hs = (const float*)d_in[0];
  const float* Wq = (const float*)d_in[1];
  const float* Wk = (const float*)d_in[2];
  const float* Wv = (const float*)d_in[3];
  const float* Wg = (const float*)d_in[4];
  const float* Wd = (const float*)d_in[5];
  const float* Wo = (const float*)d_in[6];
  float* out = (float*)d_out;

  char* ws = (char*)d_ws;
  unsigned short* hsb   = (unsigned short*)(ws);               // 16,777,216 B (dead after QKV GEMM)
  unsigned short* Wcomb = (unsigned short*)(ws + 16777216);    // 12,582,912 B  [3072][2048]
  unsigned short* Wot   = (unsigned short*)(ws + 29360128);    //  8,388,608 B
  float*  Wqg   = (float*)(ws + 37748736);                     //     32,768 B
  float*  Wvd   = (float*)(ws + 37781504);                     //     32,768 B
  float*  biasb = (float*)(ws + 37814272);                     //     65,536 B
  unsigned short* qkv = (unsigned short*)(ws + 37879808);      // 25,165,824 B  [4096][3072]
  float*  vmean = (float*)(ws + 67239936);                     //      4,096 B
  unsigned short* ob  = (unsigned short*)(ws + 67244032);      // 16,777,216 B
  // compaction buffers overlay the dead hsb region (written only after the QKV GEMM):
  unsigned short* Kc    = (unsigned short*)(ws);               //  4,194,304 B [8][2048][128]
  unsigned short* vTc   = (unsigned short*)(ws + 4194304);     //  4,194,304 B [8][128][2048]
  int*   idxArr  = (int*)(ws + 8388608);                       //     65,536 B [8][2048]
  float* biascB  = (float*)(ws + 8454144);                     //     65,536 B [8][2048]
  int*   kendArr = (int*)(ws + 8519680);                       //      1,024 B [8][32]

  const float QSCALE = 0.08838834764831845f * LOG2E;  // fold softmax scale + log2e into Q

  // 1. weight transposes (fp32 -> bf16, B^T layout); Wq pre-scaled
  {
    dim3 g1(2048 / 32, 2048 / 32);
    dim3 g2(512 / 32, 2048 / 32);
    k_transpose_w<<<g1, 256, 0, stream>>>(Wq, Wcomb, 2048, 2048, QSCALE);
    k_transpose_w<<<g2, 256, 0, stream>>>(Wk, Wcomb + (long)2048 * 2048, 2048, 512, 1.0f);
    k_transpose_w<<<g2, 256, 0, stream>>>(Wv, Wcomb + (long)2560 * 2048, 2048, 512, 1.0f);
    k_transpose_w<<<g1, 256, 0, stream>>>(Wo, Wot, 2048, 2048, 1.0f);
  }

  // 2. fused weight products for fp32 gate/delta path
  k_wproj<<<2048, 256, 0, stream>>>(Wq, Wg, Wqg, 2048);
  k_wproj<<<2048, 256, 0, stream>>>(Wv, Wd, Wvd, 512);

  // 3. bias (fp32, pre-masked + log2e-scaled) + fused hs -> bf16 conversion
  k_bias<<<4096, 256, 0, stream>>>(hs, Wqg, Wvd, biasb, hsb);

  // 4. fused QKV projection GEMM (last reader of hsb)
  {
    dim3 gq(3072 / 128, 4096 / 128);
    k_gemm_bt<1><<<gq, 256, 0, stream>>>(hsb, Wcomb, qkv, 4096, 3072, 2048);
  }

  // 5. vmean directly from qkv (uniform over ALL keys, for empty-row fallback)
  k_vmeand<<<8, 256, 0, stream>>>(qkv, vmean);

  // 6. key compaction: scan + gathers (into the dead hsb region)
  k_scan<<<8, 256, 0, stream>>>(biasb, idxArr, biascB, kendArr);
  {
    dim3 gk(128, 8);
    k_gatherk<<<gk, 256, 0, stream>>>(qkv, idxArr, Kc);
    dim3 gvt(4, 64, 8);
    k_gathervt<<<gvt, 256, 0, stream>>>(qkv, idxArr, vTc);
  }

  // 7. flash attention over compacted keys
  k_attn<<<1024, 256, 0, stream>>>(qkv, Kc, biascB, vTc, idxArr, kendArr, vmean, ob);

  // 8. output projection (fp32 out)
  {
    dim3 go(2048 / 128, 4096 / 128);
    k_gemm_bt<0><<<go, 256, 0, stream>>>(ob, Wot, out, 4096, 2048, 2048);
  }
}

// Round 7
// 343.170 us; speedup vs baseline: 1.0651x; 1.0651x over previous
//
#include <hip/hip_runtime.h>
#include <hip/hip_bf16.h>
#include <cmath>
#include <cstdint>

typedef __attribute__((ext_vector_type(8))) short short8;
typedef __attribute__((ext_vector_type(4))) float floatx4;
typedef __attribute__((ext_vector_type(4))) unsigned int uintx4;

typedef const __attribute__((address_space(1))) unsigned int* gas_p;
typedef __attribute__((address_space(3))) unsigned int* las_p;

#define LOG2E 1.4426950408889634f

__device__ inline unsigned short f2bf(float f) {
  unsigned int u = __builtin_bit_cast(unsigned int, f);
  unsigned int r = (u + 0x7FFFu + ((u >> 16) & 1u)) >> 16;
  return (unsigned short)r;
}
__device__ inline float bf2f(unsigned short h) {
  unsigned int u = ((unsigned int)h) << 16;
  return __builtin_bit_cast(float, u);
}

// ---------------- transpose + convert + scale: fp32 [K][N] -> bf16 [N][K] ----------------
__global__ void k_transpose_w(const float* __restrict__ in, unsigned short* __restrict__ out,
                              int K, int N, float scl) {
  __shared__ float t[32][33];
  int n0 = blockIdx.x * 32, k0 = blockIdx.y * 32;
  int tx = threadIdx.x & 31, ty = threadIdx.x >> 5; // 256 threads: ty 0..7
  #pragma unroll
  for (int r = ty; r < 32; r += 8)
    t[r][tx] = in[(long)(k0 + r) * N + n0 + tx];
  __syncthreads();
  #pragma unroll
  for (int r = ty; r < 32; r += 8)
    out[(long)(n0 + r) * K + k0 + tx] = f2bf(t[tx][r] * scl);
}

// ---------------- small fp32 GEMM: out[d][0..3] = W[d,:] @ Ws (Kw x 4) ----------------
__global__ void k_wproj(const float* __restrict__ W, const float* __restrict__ Ws,
                        float* __restrict__ out, int Kw) {
  int d = blockIdx.x;
  float a0 = 0, a1 = 0, a2 = 0, a3 = 0;
  for (int j = threadIdx.x; j < Kw; j += 256) {
    float w = W[(long)d * Kw + j];
    float4 g = reinterpret_cast<const float4*>(Ws)[j];
    a0 += w * g.x; a1 += w * g.y; a2 += w * g.z; a3 += w * g.w;
  }
  #pragma unroll
  for (int off = 1; off < 64; off <<= 1) {
    a0 += __shfl_xor(a0, off, 64); a1 += __shfl_xor(a1, off, 64);
    a2 += __shfl_xor(a2, off, 64); a3 += __shfl_xor(a3, off, 64);
  }
  __shared__ float red[4][4];
  if ((threadIdx.x & 63) == 0) {
    int wv = threadIdx.x >> 6;
    red[wv][0] = a0; red[wv][1] = a1; red[wv][2] = a2; red[wv][3] = a3;
  }
  __syncthreads();
  if (threadIdx.x < 4) {
    int nn = threadIdx.x;
    out[d * 4 + nn] = red[0][nn] + red[1][nn] + red[2][nn] + red[3][nn];
  }
}

// ---------------- bias (fp32), pre-masked + log2e-scaled; ALSO emits hs row as bf16 ----------------
// R13: single-pass float4 — read each hs row ONCE, feed both the bf16 conversion and the
// gate/delta dot products from the same registers (Wqg/Wvd are 32 KB, L1-resident).
__global__ void k_bias(const float* __restrict__ hs, const float* __restrict__ Wqg,
                       const float* __restrict__ Wvd, float* __restrict__ bias,
                       unsigned short* __restrict__ hsb) {
  int row = blockIdx.x;           // b*2048 + s
  int b = row >> 11, s = row & 2047;
  float g0 = 0, g1 = 0, g2 = 0, g3 = 0, d0 = 0, d1 = 0, d2 = 0, d3 = 0;
  const float4* h4 = reinterpret_cast<const float4*>(hs + (long)row * 2048);
  const float4* a4 = reinterpret_cast<const float4*>(Wqg);
  const float4* c4 = reinterpret_cast<const float4*>(Wvd);
  uint2* o2p = reinterpret_cast<uint2*>(hsb + (long)row * 2048);
  #pragma unroll
  for (int it = 0; it < 2; it++) {
    const int j4 = it * 256 + threadIdx.x;
    float4 v = h4[j4];
    uint2 o2;
    o2.x = (unsigned)f2bf(v.x) | ((unsigned)f2bf(v.y) << 16);
    o2.y = (unsigned)f2bf(v.z) | ((unsigned)f2bf(v.w) << 16);
    o2p[j4] = o2;
    const int jb = j4 * 4;
    float4 ax = a4[jb], ay = a4[jb + 1], az = a4[jb + 2], aw = a4[jb + 3];
    float4 cx = c4[jb], cy = c4[jb + 1], cz = c4[jb + 2], cw = c4[jb + 3];
    g0 += v.x * ax.x + v.y * ay.x + v.z * az.x + v.w * aw.x;
    g1 += v.x * ax.y + v.y * ay.y + v.z * az.y + v.w * aw.y;
    g2 += v.x * ax.z + v.y * ay.z + v.z * az.z + v.w * aw.z;
    g3 += v.x * ax.w + v.y * ay.w + v.z * az.w + v.w * aw.w;
    d0 += v.x * cx.x + v.y * cy.x + v.z * cz.x + v.w * cw.x;
    d1 += v.x * cx.y + v.y * cy.y + v.z * cz.y + v.w * cw.y;
    d2 += v.x * cx.z + v.y * cy.z + v.z * cz.z + v.w * cw.z;
    d3 += v.x * cx.w + v.y * cy.w + v.z * cz.w + v.w * cw.w;
  }
  #pragma unroll
  for (int off = 1; off < 64; off <<= 1) {
    g0 += __shfl_xor(g0, off, 64); g1 += __shfl_xor(g1, off, 64);
    g2 += __shfl_xor(g2, off, 64); g3 += __shfl_xor(g3, off, 64);
    d0 += __shfl_xor(d0, off, 64); d1 += __shfl_xor(d1, off, 64);
    d2 += __shfl_xor(d2, off, 64); d3 += __shfl_xor(d3, off, 64);
  }
  __shared__ float red[4][8];
  if ((threadIdx.x & 63) == 0) {
    int wv = threadIdx.x >> 6;
    red[wv][0] = g0; red[wv][1] = g1; red[wv][2] = g2; red[wv][3] = g3;
    red[wv][4] = d0; red[wv][5] = d1; red[wv][6] = d2; red[wv][7] = d3;
  }
  __syncthreads();
  if (threadIdx.x < 4) {
    int nn = threadIdx.x;
    float gg = red[0][nn] + red[1][nn] + red[2][nn] + red[3][nn];
    float dd = red[0][4 + nn] + red[1][4 + nn] + red[2][4 + nn] + red[3][4 + nn];
    float sig = 1.0f / (1.0f + __expf(-gg));
    float v = sig * dd;
    bias[(b * 4 + nn) * 2048 + s] = (v > 0.0f) ? v * LOG2E : -INFINITY;
  }
}

// ---------------- key compaction scan: per (b,n) sorted allowed-key list ----------------
__global__ void k_scan(const float* __restrict__ biasb, int* __restrict__ idx,
                       float* __restrict__ biasc, int* __restrict__ kendArr) {
  const int bn = blockIdx.x;        // 8
  const int t = threadIdx.x;        // 256, each handles 8 consecutive positions
  const float* br = biasb + bn * 2048;
  float v[8]; int pred[8]; int c = 0;
  #pragma unroll
  for (int i = 0; i < 8; i++) {
    v[i] = br[t * 8 + i];
    pred[i] = (v[i] > -1e30f) ? 1 : 0;
    c += pred[i];
  }
  __shared__ int cnts[256];
  __shared__ int offs[257];
  cnts[t] = c;
  __syncthreads();
  if (t == 0) {
    int acc = 0;
    for (int i = 0; i < 256; i++) { offs[i] = acc; acc += cnts[i]; }
    offs[256] = acc;
  }
  __syncthreads();
  int off = offs[t];
  #pragma unroll
  for (int i = 0; i < 8; i++) {
    if (pred[i]) {
      idx[bn * 2048 + off] = t * 8 + i;
      biasc[bn * 2048 + off] = v[i];
      off++;
    }
  }
  const int cnt = offs[256];
  for (int j = cnt + t; j < 2048; j += 256) {
    idx[bn * 2048 + j] = 0x7FFFFFFF;
    biasc[bn * 2048 + j] = -INFINITY;
  }
  if (t == 0) {
    for (int qt = 0; qt < 32; qt++) {
      int pc = offs[(qt + 1) * 8];
      kendArr[bn * 32 + qt] = (pc + 63) & ~63;
    }
  }
}

// ---------------- gather compacted K rows ----------------
__global__ void k_gatherk(const unsigned short* __restrict__ qkv, const int* __restrict__ idx,
                          unsigned short* __restrict__ Kc) {
  const int bn = blockIdx.y, b = bn >> 2, n = bn & 3;
  const int j = blockIdx.x * 16 + (threadIdx.x >> 4);
  const int seg = threadIdx.x & 15;
  const int s = idx[bn * 2048 + j];
  uintx4 val = {0u, 0u, 0u, 0u};
  if (s < 2048)
    val = *reinterpret_cast<const uintx4*>(qkv + ((long)(b * 2048 + s)) * 3072 + 2048 + n * 128 + seg * 8);
  *reinterpret_cast<uintx4*>(Kc + ((long)bn * 2048 + j) * 128 + seg * 8) = val;
}

// ---------------- gather + transpose compacted V: vTc[bn][hd][j] ----------------
__global__ void k_gathervt(const unsigned short* __restrict__ qkv, const int* __restrict__ idx,
                           unsigned short* __restrict__ vTc) {
  __shared__ unsigned short t[32][33];
  const int bn = blockIdx.z, b = bn >> 2, n = bn & 3;
  const int c0 = blockIdx.x * 32, j0 = blockIdx.y * 32;
  const int tx = threadIdx.x & 31, ty = threadIdx.x >> 5;
  #pragma unroll
  for (int r = ty; r < 32; r += 8) {
    const int s = idx[bn * 2048 + j0 + r];
    t[r][tx] = (s < 2048)
        ? qkv[((long)(b * 2048 + s)) * 3072 + 2560 + n * 128 + c0 + tx]
        : (unsigned short)0;
  }
  __syncthreads();
  #pragma unroll
  for (int r = ty; r < 32; r += 8)
    vTc[((long)bn * 128 + c0 + r) * 2048 + j0 + tx] = t[tx][r];
}

// ---------------- vmean stage 1: per-(bn, 128-row slab) partial column sums ----------------
// R13: R12's single 8-block k_vmeand was latency-bound on 3% of the chip (the +30 us
// regression). Two-stage: 128 blocks of slab sums, then a trivial fold.
__global__ void k_vmean_part(const unsigned short* __restrict__ qkv, float* __restrict__ part) {
  const int seg = blockIdx.x;       // 16 slabs of 128 rows
  const int bn = blockIdx.y;        // 8
  const int b = bn >> 2, n = bn & 3;
  const int t = threadIdx.x;
  const int cg = (t & 15) * 8;      // col group base (0..120)
  const int rg = t >> 4;            // row phase 0..15
  const unsigned short* base = qkv + (long)(b * 2048) * 3072 + 2560 + n * 128 + cg;
  float s[8] = {0.f, 0.f, 0.f, 0.f, 0.f, 0.f, 0.f, 0.f};
  const int r0 = seg * 128 + rg;
  #pragma unroll
  for (int i = 0; i < 8; i++) {
    uintx4 v = *reinterpret_cast<const uintx4*>(base + (long)(r0 + i * 16) * 3072);
    #pragma unroll
    for (int k = 0; k < 4; k++) {
      unsigned u = v[k];
      s[2 * k]     += bf2f((unsigned short)(u & 0xffff));
      s[2 * k + 1] += bf2f((unsigned short)(u >> 16));
    }
  }
  __shared__ float red[256][8];
  #pragma unroll
  for (int i = 0; i < 8; i++) red[t][i] = s[i];
  __syncthreads();
  if (t < 128) {
    const int colg = t >> 3, i = t & 7;   // col = colg*8 + i == t
    float acc = 0.f;
    #pragma unroll
    for (int gg = 0; gg < 16; gg++) acc += red[gg * 16 + colg][i];
    part[(bn * 16 + seg) * 128 + t] = acc;
  }
}

// ---------------- vmean stage 2: fold 16 slab partials ----------------
__global__ void k_vmean_fin(const float* __restrict__ part, float* __restrict__ vmean) {
  const int bn = blockIdx.x;   // 8
  const int c = threadIdx.x;   // 128
  float acc = 0.f;
  #pragma unroll
  for (int s = 0; s < 16; s++) acc += part[(bn * 16 + s) * 128 + c];
  vmean[bn * 128 + c] = acc * (1.0f / 2048.0f);
}

// ---------------- bf16 MFMA GEMM: C[M,N] = A[M,K] @ Bt[N,K]^T ----------------
template <int WRITE_BF16>
__global__ __launch_bounds__(256, 2) void k_gemm_bt(
    const unsigned short* __restrict__ A, const unsigned short* __restrict__ Bt,
    void* __restrict__ Cout, int M, int N, int K) {
  __shared__ __align__(16) unsigned short As[128 * 32];
  __shared__ __align__(16) unsigned short Bs[128 * 32];
  const int tid = threadIdx.x;
  const int lane = tid & 63, wave = tid >> 6;
  const int quad = lane >> 4, l16 = lane & 15;
  const long bm = (long)blockIdx.y * 128, bn = (long)blockIdx.x * 128;
  const int wm = (wave >> 1) * 64, wn = (wave & 1) * 64;

  const floatx4 fz = {0.f, 0.f, 0.f, 0.f};
  floatx4 acc[4][4];
  #pragma unroll
  for (int i = 0; i < 4; i++)
    #pragma unroll
    for (int j = 0; j < 4; j++) acc[i][j] = fz;

  const int r0 = tid >> 2, c0 = (tid & 3) * 8;
  const unsigned short* Ag = A + (bm + r0) * K + c0;
  const unsigned short* Bg = Bt + (bn + r0) * K + c0;
  unsigned short* AsW0 = As + (wave * 16) * 32;
  unsigned short* AsW1 = As + (wave * 16 + 64) * 32;
  unsigned short* BsW0 = Bs + (wave * 16) * 32;
  unsigned short* BsW1 = Bs + (wave * 16 + 64) * 32;

  for (int kt = 0; kt < K; kt += 32) {
    __syncthreads();
    __builtin_amdgcn_global_load_lds((gas_p)(const void*)(Ag + kt),
                                     (las_p)(void*)AsW0, 16, 0, 0);
    __builtin_amdgcn_global_load_lds((gas_p)(const void*)(Ag + (long)64 * K + kt),
                                     (las_p)(void*)AsW1, 16, 0, 0);
    __builtin_amdgcn_global_load_lds((gas_p)(const void*)(Bg + kt),
                                     (las_p)(void*)BsW0, 16, 0, 0);
    __builtin_amdgcn_global_load_lds((gas_p)(const void*)(Bg + (long)64 * K + kt),
                                     (las_p)(void*)BsW1, 16, 0, 0);
    __syncthreads();
    short8 af[4], bf[4];
    #pragma unroll
    for (int i = 0; i < 4; i++)
      af[i] = *reinterpret_cast<const short8*>(&As[(wm + i * 16 + l16) * 32 + quad * 8]);
    #pragma unroll
    for (int j = 0; j < 4; j++)
      bf[j] = *reinterpret_cast<const short8*>(&Bs[(wn + j * 16 + l16) * 32 + quad * 8]);
    #pragma unroll
    for (int i = 0; i < 4; i++)
      #pragma unroll
      for (int j = 0; j < 4; j++)
        acc[i][j] = __builtin_amdgcn_mfma_f32_16x16x32_bf16(af[i], bf[j], acc[i][j], 0, 0, 0);
  }
  #pragma unroll
  for (int i = 0; i < 4; i++)
    #pragma unroll
    for (int j = 0; j < 4; j++)
      #pragma unroll
      for (int r = 0; r < 4; r++) {
        const long row = bm + wm + i * 16 + quad * 4 + r;
        const long col = bn + wn + j * 16 + l16;
        const float v = acc[i][j][r];
        if (WRITE_BF16)
          ((unsigned short*)Cout)[row * N + col] = f2bf(v);
        else
          ((float*)Cout)[row * N + col] = v;
      }
}

// ---------------- flash attention over COMPACTED keys (dynamic mask exploited) ----------------
// R11 structure unchanged (harness-verified): K/V/bias pre-compacted to keys with bias > 0,
// causal test via original-position LDS tile Is, kend ~halved.
// grid 1024 = qt(32, LPT) x b(2) x n(4) x g(4); 4 waves; wave owns 16 q rows.
// LDS: Ks 64x144 + Vs 128x72 + Ps 4x16x72 + Is 64 ints = 46,336 B -> 3 blocks/CU.
__global__ __launch_bounds__(256, 3) void k_attn(
    const unsigned short* __restrict__ qkv,   // [4096][3072] (q | k | v); q pre-scaled
    const unsigned short* __restrict__ Kc,    // [8][2048][128] compacted K (pads zero)
    const float* __restrict__ biasc,          // [8][2048] compacted bias (pads -INF)
    const unsigned short* __restrict__ vTc,   // [8][128][2048] compacted V^T (pads zero)
    const int* __restrict__ idxArr,           // [8][2048] original positions (pads INT_MAX)
    const int* __restrict__ kendArr,          // [8][32]
    const float* __restrict__ vmean,          // [1024]
    unsigned short* __restrict__ o)           // [4096][2048]
{
  int idx = blockIdx.x;
  const int g = idx & 3;
  const int n = (idx >> 2) & 3;
  const int b = (idx >> 4) & 1;
  const int qt = 31 - (idx >> 5);            // 64-row q tiles, big blocks dispatch first (LPT)
  const int tid = threadIdx.x, lane = tid & 63, wave = tid >> 6;
  const int quad = lane >> 4, l16 = lane & 15;
  const int q0 = qt * 64 + wave * 16;
  const int bn = b * 4 + n;

  __shared__ __align__(16) unsigned short Ks[64 * 144];
  __shared__ __align__(16) unsigned short Vs[128 * 72];
  __shared__ __align__(16) unsigned short Ps[4 * 16 * 72];
  __shared__ __align__(16) int Is[64];
  unsigned short* Psw = Ps + wave * 1152;    // 16 x 72 [q][key], per-wave private

  // Q fragments (B-operand for K@Q^T): row=q0+l16, k=ks*32+quad*8..+8
  short8 qf[4];
  {
    const unsigned short* qp = qkv + (long)(b * 2048) * 3072 + (n * 4 + g) * 128;
    #pragma unroll
    for (int ks = 0; ks < 4; ks++)
      qf[ks] = *reinterpret_cast<const short8*>(
          qp + (long)(q0 + l16) * 3072 + ks * 32 + quad * 8);
  }

  const floatx4 fz = {0.f, 0.f, 0.f, 0.f};
  floatx4 oacc[8];
  #pragma unroll
  for (int j = 0; j < 8; j++) oacc[j] = fz;
  float mrow = -INFINITY, lrow = 0.0f;       // per-lane: q = q0 + l16 (replicated across quads)

  const float* biasrow = biasc + bn * 2048;
  const unsigned short* kbase = Kc + (long)bn * 2048 * 128;
  const unsigned short* vbase = vTc + (long)bn * 128 * 2048;
  const int* idxp = idxArr + bn * 2048;
  const int kend = kendArr[bn * 32 + qt];
  const int kk_ = tid >> 4, hdo_ = (tid & 15) * 8;   // K staging coords (row += 16/pass)
  const int hd_ = tid >> 3, ko_ = (tid & 7) * 8;     // V staging coords (row += 32/pass)

  uintx4 kreg[4], vreg[4];
  float4 breg[4];
  int ireg;
  // prologue: load tile 0
  {
    #pragma unroll
    for (int it = 0; it < 4; it++)
      kreg[it] = *reinterpret_cast<const uintx4*>(kbase + (long)(kk_ + it * 16) * 128 + hdo_);
    #pragma unroll
    for (int it = 0; it < 4; it++)
      vreg[it] = *reinterpret_cast<const uintx4*>(vbase + (long)(hd_ + it * 32) * 2048 + ko_);
    #pragma unroll
    for (int kt = 0; kt < 4; kt++)
      breg[kt] = *reinterpret_cast<const float4*>(biasrow + kt * 16 + quad * 4);
    ireg = idxp[tid & 63];
  }

  for (int k0 = 0; k0 < kend; k0 += 64) {
    __syncthreads();  // (A) all waves done with LDS reads of previous tile
    // commit prefetched tile to LDS
    #pragma unroll
    for (int it = 0; it < 4; it++)
      *reinterpret_cast<uintx4*>(&Ks[(kk_ + it * 16) * 144 + hdo_]) = kreg[it];
    #pragma unroll
    for (int it = 0; it < 4; it++)
      *reinterpret_cast<uintx4*>(&Vs[(hd_ + it * 32) * 72 + ko_]) = vreg[it];
    if (tid < 64) Is[tid] = ireg;
    float4 bcur[4];
    #pragma unroll
    for (int kt = 0; kt < 4; kt++) bcur[kt] = breg[kt];

    // issue next tile's loads (land during this tile's compute)
    if (k0 + 64 < kend) {
      const unsigned short* kp = kbase + (long)(k0 + 64) * 128;
      const unsigned short* vp = vbase + (k0 + 64);
      #pragma unroll
      for (int it = 0; it < 4; it++)
        kreg[it] = *reinterpret_cast<const uintx4*>(kp + (long)(kk_ + it * 16) * 128 + hdo_);
      #pragma unroll
      for (int it = 0; it < 4; it++)
        vreg[it] = *reinterpret_cast<const uintx4*>(vp + (long)(hd_ + it * 32) * 2048 + ko_);
      #pragma unroll
      for (int kt = 0; kt < 4; kt++)
        breg[kt] = *reinterpret_cast<const float4*>(biasrow + (k0 + 64) + kt * 16 + quad * 4);
      ireg = idxp[k0 + 64 + (tid & 63)];
    }
    __syncthreads();  // (B) staged tile visible

    const int ifirst = Is[0];
    const bool active = (ifirst <= q0 + 15);
    if (active) {
      // S^T tile: sacc[kt] rows = compacted keys k0+kt*16+quad*4+r, col = q0+l16. C-init = bias.
      floatx4 sacc[4];
      #pragma unroll
      for (int kt = 0; kt < 4; kt++)
        sacc[kt] = (floatx4){bcur[kt].x, bcur[kt].y, bcur[kt].z, bcur[kt].w};
      __builtin_amdgcn_s_setprio(1);
      #pragma unroll
      for (int ks = 0; ks < 4; ks++) {
        short8 kf[4];
        #pragma unroll
        for (int kt = 0; kt < 4; kt++)
          kf[kt] = *reinterpret_cast<const short8*>(&Ks[(kt * 16 + l16) * 144 + ks * 32 + quad * 8]);
        #pragma unroll
        for (int kt = 0; kt < 4; kt++)
          sacc[kt] = __builtin_amdgcn_mfma_f32_16x16x32_bf16(kf[kt], qf[ks], sacc[kt], 0, 0, 0);
      }
      __builtin_amdgcn_s_setprio(0);

      // softmax (register-only): causal mask via original positions, in-lane max/sum + 2 shfls
      const int ilast = Is[63];
      const bool full = (ilast <= q0);
      if (!full) {
        const int qme = q0 + l16;
        #pragma unroll
        for (int kt = 0; kt < 4; kt++) {
          const int4 iq = *reinterpret_cast<const int4*>(&Is[kt * 16 + quad * 4]);
          if (iq.x > qme) sacc[kt][0] = -INFINITY;
          if (iq.y > qme) sacc[kt][1] = -INFINITY;
          if (iq.z > qme) sacc[kt][2] = -INFINITY;
          if (iq.w > qme) sacc[kt][3] = -INFINITY;
        }
      }
      float mx = -INFINITY;
      #pragma unroll
      for (int kt = 0; kt < 4; kt++)
        #pragma unroll
        for (int r = 0; r < 4; r++) mx = fmaxf(mx, sacc[kt][r]);
      mx = fmaxf(mx, __shfl_xor(mx, 16, 64));
      mx = fmaxf(mx, __shfl_xor(mx, 32, 64));
      const float mn = fmaxf(mrow, mx);
      const float mnc = fmaxf(mn, -1e38f);
      const float alpha = __builtin_amdgcn_exp2f(mrow - mnc);
      float rs = 0.0f;
      unsigned pk[4][2];
      #pragma unroll
      for (int kt = 0; kt < 4; kt++) {
        #pragma unroll
        for (int r = 0; r < 4; r++) {
          float p = __builtin_amdgcn_exp2f(sacc[kt][r] - mnc);
          sacc[kt][r] = p;
          rs += p;
        }
        #pragma unroll
        for (int r2 = 0; r2 < 2; r2++)
          pk[kt][r2] = (unsigned)f2bf(sacc[kt][2 * r2]) | ((unsigned)f2bf(sacc[kt][2 * r2 + 1]) << 16);
      }
      rs += __shfl_xor(rs, 16, 64);
      rs += __shfl_xor(rs, 32, 64);
      mrow = mn;
      lrow = lrow * alpha + rs;

      // rescale O: alpha in q=l16 space -> oacc q=quad*4+r space via bpermute
      float al[4];
      #pragma unroll
      for (int r = 0; r < 4; r++) al[r] = __shfl(alpha, quad * 4 + r, 64);
      #pragma unroll
      for (int j = 0; j < 8; j++)
        #pragma unroll
        for (int r = 0; r < 4; r++) oacc[j][r] *= al[r];

      // store packed P to Psw[q=l16][key] (own buffer, wave-private: no barrier)
      unsigned* Pd = reinterpret_cast<unsigned*>(Psw);
      #pragma unroll
      for (int kt = 0; kt < 4; kt++)
        #pragma unroll
        for (int r2 = 0; r2 < 2; r2++)
          Pd[l16 * 36 + kt * 8 + quad * 2 + r2] = pk[kt][r2];

      // O += P @ V  (A = P [q][key], B = V^T [key][hd])
      __builtin_amdgcn_s_setprio(1);
      #pragma unroll
      for (int ks2 = 0; ks2 < 2; ks2++) {
        short8 pf = *reinterpret_cast<const short8*>(&Psw[l16 * 72 + ks2 * 32 + quad * 8]);
        #pragma unroll
        for (int j = 0; j < 8; j++) {
          short8 vf = *reinterpret_cast<const short8*>(&Vs[(j * 16 + l16) * 72 + ks2 * 32 + quad * 8]);
          oacc[j] = __builtin_amdgcn_mfma_f32_16x16x32_bf16(pf, vf, oacc[j], 0, 0, 0);
        }
      }
      __builtin_amdgcn_s_setprio(0);
    }
  }

  // epilogue: oacc rows q=q0+quad*4+r; l lives in q=l16 space -> bpermute
  const long obase = (long)(b * 2048) * 2048 + (n * 4 + g) * 128;
  #pragma unroll
  for (int r = 0; r < 4; r++) {
    const int qrow = q0 + quad * 4 + r;
    const float l = __shfl(lrow, quad * 4 + r, 64);
    const float inv = (l > 0.0f) ? 1.0f / l : 0.0f;
    #pragma unroll
    for (int j = 0; j < 8; j++) {
      const int hd = j * 16 + l16;
      float v = oacc[j][r] * inv;
      if (l <= 0.0f) v = vmean[(b * 4 + n) * 128 + hd];  // empty row: uniform softmax over ALL keys
      o[obase + (long)qrow * 2048 + hd] = f2bf(v);
    }
  }
}

extern "C" void kernel_launch(void* const* d_in, const int* in_sizes, int n_in,
                              void* d_out, int out_size, void* d_ws, size_t ws_size,
                              hipStream_t stream) {
  const float* hs = (const float*)d_in[0];
  const float* Wq = (const float*)d_in[1];
  const float* Wk = (const float*)d_in[2];
  const float* Wv = (const float*)d_in[3];
  const float* Wg = (const float*)d_in[4];
  const float* Wd = (const float*)d_in[5];
  const float* Wo = (const float*)d_in[6];
  float* out = (float*)d_out;

  char* ws = (char*)d_ws;
  unsigned short* hsb   = (unsigned short*)(ws);               // 16,777,216 B (dead after QKV GEMM)
  unsigned short* Wcomb = (unsigned short*)(ws + 16777216);    // 12,582,912 B  [3072][2048]
  unsigned short* Wot   = (unsigned short*)(ws + 29360128);    //  8,388,608 B
  float*  Wqg   = (float*)(ws + 37748736);                     //     32,768 B
  float*  Wvd   = (float*)(ws + 37781504);                     //     32,768 B
  float*  biasb = (float*)(ws + 37814272);                     //     65,536 B
  unsigned short* qkv = (unsigned short*)(ws + 37879808);      // 25,165,824 B  [4096][3072]
  float*  vmean = (float*)(ws + 67239936);                     //      4,096 B
  unsigned short* ob  = (unsigned short*)(ws + 67244032);      // 16,777,216 B
  // compaction + vmean buffers overlay the dead hsb region (written only after the QKV GEMM):
  unsigned short* Kc    = (unsigned short*)(ws);               //  4,194,304 B [8][2048][128]
  unsigned short* vTc   = (unsigned short*)(ws + 4194304);     //  4,194,304 B [8][128][2048]
  int*   idxArr  = (int*)(ws + 8388608);                       //     65,536 B [8][2048]
  float* biascB  = (float*)(ws + 8454144);                     //     65,536 B [8][2048]
  int*   kendArr = (int*)(ws + 8519680);                       //      1,024 B [8][32]
  float* vmpart  = (float*)(ws + 8520704);                     //     65,536 B [128][128]

  const float QSCALE = 0.08838834764831845f * LOG2E;  // fold softmax scale + log2e into Q

  // 1. weight transposes (fp32 -> bf16, B^T layout); Wq pre-scaled
  {
    dim3 g1(2048 / 32, 2048 / 32);
    dim3 g2(512 / 32, 2048 / 32);
    k_transpose_w<<<g1, 256, 0, stream>>>(Wq, Wcomb, 2048, 2048, QSCALE);
    k_transpose_w<<<g2, 256, 0, stream>>>(Wk, Wcomb + (long)2048 * 2048, 2048, 512, 1.0f);
    k_transpose_w<<<g2, 256, 0, stream>>>(Wv, Wcomb + (long)2560 * 2048, 2048, 512, 1.0f);
    k_transpose_w<<<g1, 256, 0, stream>>>(Wo, Wot, 2048, 2048, 1.0f);
  }

  // 2. fused weight products for fp32 gate/delta path
  k_wproj<<<2048, 256, 0, stream>>>(Wq, Wg, Wqg, 2048);
  k_wproj<<<2048, 256, 0, stream>>>(Wv, Wd, Wvd, 512);

  // 3. bias (fp32, pre-masked + log2e-scaled) + fused hs -> bf16 conversion (single pass)
  k_bias<<<4096, 256, 0, stream>>>(hs, Wqg, Wvd, biasb, hsb);

  // 4. fused QKV projection GEMM (last reader of hsb)
  {
    dim3 gq(3072 / 128, 4096 / 128);
    k_gemm_bt<1><<<gq, 256, 0, stream>>>(hsb, Wcomb, qkv, 4096, 3072, 2048);
  }

  // 5. vmean from qkv (two-stage, 128-block parallel; uniform over ALL keys)
  {
    dim3 gp(16, 8);
    k_vmean_part<<<gp, 256, 0, stream>>>(qkv, vmpart);
    k_vmean_fin<<<8, 128, 0, stream>>>(vmpart, vmean);
  }

  // 6. key compaction: scan + gathers (into the dead hsb region)
  k_scan<<<8, 256, 0, stream>>>(biasb, idxArr, biascB, kendArr);
  {
    dim3 gk(128, 8);
    k_gatherk<<<gk, 256, 0, stream>>>(qkv, idxArr, Kc);
    dim3 gvt(4, 64, 8);
    k_gathervt<<<gvt, 256, 0, stream>>>(qkv, idxArr, vTc);
  }

  // 7. flash attention over compacted keys
  k_attn<<<1024, 256, 0, stream>>>(qkv, Kc, biascB, vTc, idxArr, kendArr, vmean, ob);

  // 8. output projection (fp32 out)
  {
    dim3 go(2048 / 128, 4096 / 128);
    k_gemm_bt<0><<<go, 256, 0, stream>>>(ob, Wot, out, 4096, 2048, 2048);
  }
}

// Round 8
// 314.652 us; speedup vs baseline: 1.1617x; 1.0906x over previous
//
#include <hip/hip_runtime.h>
#include <hip/hip_bf16.h>
#include <cmath>
#include <cstdint>

typedef __attribute__((ext_vector_type(8))) short short8;
typedef __attribute__((ext_vector_type(4))) float floatx4;
typedef __attribute__((ext_vector_type(4))) unsigned int uintx4;

typedef const __attribute__((address_space(1))) unsigned int* gas_p;
typedef __attribute__((address_space(3))) unsigned int* las_p;

#define LOG2E 1.4426950408889634f

__device__ inline unsigned short f2bf(float f) {
  unsigned int u = __builtin_bit_cast(unsigned int, f);
  unsigned int r = (u + 0x7FFFu + ((u >> 16) & 1u)) >> 16;
  return (unsigned short)r;
}
__device__ inline float bf2f(unsigned short h) {
  unsigned int u = ((unsigned int)h) << 16;
  return __builtin_bit_cast(float, u);
}

// ---------------- ALL weight transposes in one launch (R14: 4 kernels -> 1) ----------------
// fp32 [K=2048][N] -> bf16 [N][K], tile 32x32. Flattened grid, range-decoded:
//   [0,4096)      Wq  (N=2048) -> Wcomb,           scl=QSCALE
//   [4096,5120)   Wk  (N=512)  -> Wcomb+2048*2048, scl=1
//   [5120,6144)   Wv  (N=512)  -> Wcomb+2560*2048, scl=1
//   [6144,10240)  Wo  (N=2048) -> Wot,             scl=1
__global__ void k_transpose_w_all(const float* __restrict__ Wq, const float* __restrict__ Wk,
                                  const float* __restrict__ Wv, const float* __restrict__ Wo,
                                  unsigned short* __restrict__ Wcomb, unsigned short* __restrict__ Wot,
                                  float qscale) {
  __shared__ float t[32][33];
  const int bid = blockIdx.x;
  const float* in; unsigned short* out; int N; float scl; int xt, yt;
  if (bid < 4096)        { in = Wq; out = Wcomb;                      N = 2048; scl = qscale; int r = bid;        xt = r & 63; yt = r >> 6; }
  else if (bid < 5120)   { in = Wk; out = Wcomb + (long)2048 * 2048;  N = 512;  scl = 1.0f;   int r = bid - 4096; xt = r & 15; yt = r >> 4; }
  else if (bid < 6144)   { in = Wv; out = Wcomb + (long)2560 * 2048;  N = 512;  scl = 1.0f;   int r = bid - 5120; xt = r & 15; yt = r >> 4; }
  else                   { in = Wo; out = Wot;                        N = 2048; scl = 1.0f;   int r = bid - 6144; xt = r & 63; yt = r >> 6; }
  const int K = 2048;
  const int n0 = xt * 32, k0 = yt * 32;
  const int tx = threadIdx.x & 31, ty = threadIdx.x >> 5;
  #pragma unroll
  for (int r = ty; r < 32; r += 8)
    t[r][tx] = in[(long)(k0 + r) * N + n0 + tx];
  __syncthreads();
  #pragma unroll
  for (int r = ty; r < 32; r += 8)
    out[(long)(n0 + r) * K + k0 + tx] = f2bf(t[tx][r] * scl);
}

// ---------------- both weight products in one launch (R14: 2 kernels -> 1) ----------------
// y=0: Wqg[d] = Wq[d,:] @ Wg (Kw=2048);  y=1: Wvd[d] = Wv[d,:] @ Wd (Kw=512)
__global__ void k_wproj_all(const float* __restrict__ Wq, const float* __restrict__ Wg,
                            const float* __restrict__ Wv, const float* __restrict__ Wd,
                            float* __restrict__ Wqg, float* __restrict__ Wvd) {
  const int d = blockIdx.x;
  const int which = blockIdx.y;
  const float* W  = which ? Wv : Wq;
  const float* Ws = which ? Wd : Wg;
  float* out      = which ? Wvd : Wqg;
  const int Kw    = which ? 512 : 2048;
  float a0 = 0, a1 = 0, a2 = 0, a3 = 0;
  for (int j = threadIdx.x; j < Kw; j += 256) {
    float w = W[(long)d * Kw + j];
    float4 g = reinterpret_cast<const float4*>(Ws)[j];
    a0 += w * g.x; a1 += w * g.y; a2 += w * g.z; a3 += w * g.w;
  }
  #pragma unroll
  for (int off = 1; off < 64; off <<= 1) {
    a0 += __shfl_xor(a0, off, 64); a1 += __shfl_xor(a1, off, 64);
    a2 += __shfl_xor(a2, off, 64); a3 += __shfl_xor(a3, off, 64);
  }
  __shared__ float red[4][4];
  if ((threadIdx.x & 63) == 0) {
    int wv = threadIdx.x >> 6;
    red[wv][0] = a0; red[wv][1] = a1; red[wv][2] = a2; red[wv][3] = a3;
  }
  __syncthreads();
  if (threadIdx.x < 4) {
    int nn = threadIdx.x;
    out[d * 4 + nn] = red[0][nn] + red[1][nn] + red[2][nn] + red[3][nn];
  }
}

// ---------------- bias (fp32), pre-masked + log2e-scaled; ALSO emits hs row as bf16 ----------------
__global__ void k_bias(const float* __restrict__ hs, const float* __restrict__ Wqg,
                       const float* __restrict__ Wvd, float* __restrict__ bias,
                       unsigned short* __restrict__ hsb) {
  int row = blockIdx.x;           // b*2048 + s
  int b = row >> 11, s = row & 2047;
  float g0 = 0, g1 = 0, g2 = 0, g3 = 0, d0 = 0, d1 = 0, d2 = 0, d3 = 0;
  const float4* h4 = reinterpret_cast<const float4*>(hs + (long)row * 2048);
  const float4* a4 = reinterpret_cast<const float4*>(Wqg);
  const float4* c4 = reinterpret_cast<const float4*>(Wvd);
  uint2* o2p = reinterpret_cast<uint2*>(hsb + (long)row * 2048);
  #pragma unroll
  for (int it = 0; it < 2; it++) {
    const int j4 = it * 256 + threadIdx.x;
    float4 v = h4[j4];
    uint2 o2;
    o2.x = (unsigned)f2bf(v.x) | ((unsigned)f2bf(v.y) << 16);
    o2.y = (unsigned)f2bf(v.z) | ((unsigned)f2bf(v.w) << 16);
    o2p[j4] = o2;
    const int jb = j4 * 4;
    float4 ax = a4[jb], ay = a4[jb + 1], az = a4[jb + 2], aw = a4[jb + 3];
    float4 cx = c4[jb], cy = c4[jb + 1], cz = c4[jb + 2], cw = c4[jb + 3];
    g0 += v.x * ax.x + v.y * ay.x + v.z * az.x + v.w * aw.x;
    g1 += v.x * ax.y + v.y * ay.y + v.z * az.y + v.w * aw.y;
    g2 += v.x * ax.z + v.y * ay.z + v.z * az.z + v.w * aw.z;
    g3 += v.x * ax.w + v.y * ay.w + v.z * az.w + v.w * aw.w;
    d0 += v.x * cx.x + v.y * cy.x + v.z * cz.x + v.w * cw.x;
    d1 += v.x * cx.y + v.y * cy.y + v.z * cz.y + v.w * cw.y;
    d2 += v.x * cx.z + v.y * cy.z + v.z * cz.z + v.w * cw.z;
    d3 += v.x * cx.w + v.y * cy.w + v.z * cz.w + v.w * cw.w;
  }
  #pragma unroll
  for (int off = 1; off < 64; off <<= 1) {
    g0 += __shfl_xor(g0, off, 64); g1 += __shfl_xor(g1, off, 64);
    g2 += __shfl_xor(g2, off, 64); g3 += __shfl_xor(g3, off, 64);
    d0 += __shfl_xor(d0, off, 64); d1 += __shfl_xor(d1, off, 64);
    d2 += __shfl_xor(d2, off, 64); d3 += __shfl_xor(d3, off, 64);
  }
  __shared__ float red[4][8];
  if ((threadIdx.x & 63) == 0) {
    int wv = threadIdx.x >> 6;
    red[wv][0] = g0; red[wv][1] = g1; red[wv][2] = g2; red[wv][3] = g3;
    red[wv][4] = d0; red[wv][5] = d1; red[wv][6] = d2; red[wv][7] = d3;
  }
  __syncthreads();
  if (threadIdx.x < 4) {
    int nn = threadIdx.x;
    float gg = red[0][nn] + red[1][nn] + red[2][nn] + red[3][nn];
    float dd = red[0][4 + nn] + red[1][4 + nn] + red[2][4 + nn] + red[3][4 + nn];
    float sig = 1.0f / (1.0f + __expf(-gg));
    float v = sig * dd;
    bias[(b * 4 + nn) * 2048 + s] = (v > 0.0f) ? v * LOG2E : -INFINITY;
  }
}

// ---------------- scan + vmean stage 1 in one launch (R14) ----------------
// blocks [0,8): compaction scan per bn. blocks [8,136): vmean 128-row slab partial sums.
__global__ void k_scan_vmp(const float* __restrict__ biasb, const unsigned short* __restrict__ qkv,
                           int* __restrict__ idx, float* __restrict__ biasc,
                           int* __restrict__ kendArr, float* __restrict__ part) {
  const int bid = blockIdx.x;
  const int t = threadIdx.x;
  if (bid < 8) {
    // ------- scan role (body identical to R11/R13 k_scan) -------
    const int bn = bid;
    const float* br = biasb + bn * 2048;
    float v[8]; int pred[8]; int c = 0;
    #pragma unroll
    for (int i = 0; i < 8; i++) {
      v[i] = br[t * 8 + i];
      pred[i] = (v[i] > -1e30f) ? 1 : 0;
      c += pred[i];
    }
    __shared__ int cnts[256];
    __shared__ int offs[257];
    cnts[t] = c;
    __syncthreads();
    if (t == 0) {
      int acc = 0;
      for (int i = 0; i < 256; i++) { offs[i] = acc; acc += cnts[i]; }
      offs[256] = acc;
    }
    __syncthreads();
    int off = offs[t];
    #pragma unroll
    for (int i = 0; i < 8; i++) {
      if (pred[i]) {
        idx[bn * 2048 + off] = t * 8 + i;
        biasc[bn * 2048 + off] = v[i];
        off++;
      }
    }
    const int cnt = offs[256];
    for (int j = cnt + t; j < 2048; j += 256) {
      idx[bn * 2048 + j] = 0x7FFFFFFF;
      biasc[bn * 2048 + j] = -INFINITY;
    }
    if (t == 0) {
      for (int qt = 0; qt < 32; qt++) {
        int pc = offs[(qt + 1) * 8];
        kendArr[bn * 32 + qt] = (pc + 63) & ~63;
      }
    }
  } else {
    // ------- vmean_part role (body identical to R13) -------
    const int p = bid - 8;
    const int seg = p & 15, bn = p >> 4;
    const int b = bn >> 2, n = bn & 3;
    const int cg = (t & 15) * 8;
    const int rg = t >> 4;
    const unsigned short* base = qkv + (long)(b * 2048) * 3072 + 2560 + n * 128 + cg;
    float s[8] = {0.f, 0.f, 0.f, 0.f, 0.f, 0.f, 0.f, 0.f};
    const int r0 = seg * 128 + rg;
    #pragma unroll
    for (int i = 0; i < 8; i++) {
      uintx4 v = *reinterpret_cast<const uintx4*>(base + (long)(r0 + i * 16) * 3072);
      #pragma unroll
      for (int k = 0; k < 4; k++) {
        unsigned u = v[k];
        s[2 * k]     += bf2f((unsigned short)(u & 0xffff));
        s[2 * k + 1] += bf2f((unsigned short)(u >> 16));
      }
    }
    __shared__ float red[256][8];
    #pragma unroll
    for (int i = 0; i < 8; i++) red[t][i] = s[i];
    __syncthreads();
    if (t < 128) {
      const int colg = t >> 3, i = t & 7;
      float acc = 0.f;
      #pragma unroll
      for (int gg = 0; gg < 16; gg++) acc += red[gg * 16 + colg][i];
      part[(bn * 16 + seg) * 128 + t] = acc;
    }
  }
}

// ---------------- gathers + vmean fold in one launch (R14) ----------------
// blocks [0,1024): K-gather; [1024,3072): V-gather+transpose; [3072,3080): vmean fold.
__global__ void k_gather_all(const unsigned short* __restrict__ qkv, const int* __restrict__ idx,
                             unsigned short* __restrict__ Kc, unsigned short* __restrict__ vTc,
                             const float* __restrict__ part, float* __restrict__ vmean) {
  const int bid = blockIdx.x;
  if (bid < 1024) {
    // ------- K-gather (identical to R13 k_gatherk) -------
    const int bn = bid >> 7, x = bid & 127;
    const int b = bn >> 2, n = bn & 3;
    const int j = x * 16 + (threadIdx.x >> 4);
    const int seg = threadIdx.x & 15;
    const int s = idx[bn * 2048 + j];
    uintx4 val = {0u, 0u, 0u, 0u};
    if (s < 2048)
      val = *reinterpret_cast<const uintx4*>(qkv + ((long)(b * 2048 + s)) * 3072 + 2048 + n * 128 + seg * 8);
    *reinterpret_cast<uintx4*>(Kc + ((long)bn * 2048 + j) * 128 + seg * 8) = val;
  } else if (bid < 3072) {
    // ------- V-gather + transpose (identical to R13 k_gathervt) -------
    __shared__ unsigned short t[32][33];
    const int vt = bid - 1024;
    const int bn = vt >> 8, r8 = vt & 255;
    const int b = bn >> 2, n = bn & 3;
    const int c0 = (r8 & 3) * 32, j0 = (r8 >> 2) * 32;
    const int tx = threadIdx.x & 31, ty = threadIdx.x >> 5;
    #pragma unroll
    for (int r = ty; r < 32; r += 8) {
      const int s = idx[bn * 2048 + j0 + r];
      t[r][tx] = (s < 2048)
          ? qkv[((long)(b * 2048 + s)) * 3072 + 2560 + n * 128 + c0 + tx]
          : (unsigned short)0;
    }
    __syncthreads();
    #pragma unroll
    for (int r = ty; r < 32; r += 8)
      vTc[((long)bn * 128 + c0 + r) * 2048 + j0 + tx] = t[tx][r];
  } else {
    // ------- vmean fold (identical to R13 k_vmean_fin) -------
    const int bn = bid - 3072;
    const int c = threadIdx.x;
    if (c < 128) {
      float acc = 0.f;
      #pragma unroll
      for (int s = 0; s < 16; s++) acc += part[(bn * 16 + s) * 128 + c];
      vmean[bn * 128 + c] = acc * (1.0f / 2048.0f);
    }
  }
}

// ---------------- bf16 MFMA GEMM: C[M,N] = A[M,K] @ Bt[N,K]^T ----------------
template <int WRITE_BF16>
__global__ __launch_bounds__(256, 2) void k_gemm_bt(
    const unsigned short* __restrict__ A, const unsigned short* __restrict__ Bt,
    void* __restrict__ Cout, int M, int N, int K) {
  __shared__ __align__(16) unsigned short As[128 * 32];
  __shared__ __align__(16) unsigned short Bs[128 * 32];
  const int tid = threadIdx.x;
  const int lane = tid & 63, wave = tid >> 6;
  const int quad = lane >> 4, l16 = lane & 15;
  const long bm = (long)blockIdx.y * 128, bn = (long)blockIdx.x * 128;
  const int wm = (wave >> 1) * 64, wn = (wave & 1) * 64;

  const floatx4 fz = {0.f, 0.f, 0.f, 0.f};
  floatx4 acc[4][4];
  #pragma unroll
  for (int i = 0; i < 4; i++)
    #pragma unroll
    for (int j = 0; j < 4; j++) acc[i][j] = fz;

  const int r0 = tid >> 2, c0 = (tid & 3) * 8;
  const unsigned short* Ag = A + (bm + r0) * K + c0;
  const unsigned short* Bg = Bt + (bn + r0) * K + c0;
  unsigned short* AsW0 = As + (wave * 16) * 32;
  unsigned short* AsW1 = As + (wave * 16 + 64) * 32;
  unsigned short* BsW0 = Bs + (wave * 16) * 32;
  unsigned short* BsW1 = Bs + (wave * 16 + 64) * 32;

  for (int kt = 0; kt < K; kt += 32) {
    __syncthreads();
    __builtin_amdgcn_global_load_lds((gas_p)(const void*)(Ag + kt),
                                     (las_p)(void*)AsW0, 16, 0, 0);
    __builtin_amdgcn_global_load_lds((gas_p)(const void*)(Ag + (long)64 * K + kt),
                                     (las_p)(void*)AsW1, 16, 0, 0);
    __builtin_amdgcn_global_load_lds((gas_p)(const void*)(Bg + kt),
                                     (las_p)(void*)BsW0, 16, 0, 0);
    __builtin_amdgcn_global_load_lds((gas_p)(const void*)(Bg + (long)64 * K + kt),
                                     (las_p)(void*)BsW1, 16, 0, 0);
    __syncthreads();
    short8 af[4], bf[4];
    #pragma unroll
    for (int i = 0; i < 4; i++)
      af[i] = *reinterpret_cast<const short8*>(&As[(wm + i * 16 + l16) * 32 + quad * 8]);
    #pragma unroll
    for (int j = 0; j < 4; j++)
      bf[j] = *reinterpret_cast<const short8*>(&Bs[(wn + j * 16 + l16) * 32 + quad * 8]);
    #pragma unroll
    for (int i = 0; i < 4; i++)
      #pragma unroll
      for (int j = 0; j < 4; j++)
        acc[i][j] = __builtin_amdgcn_mfma_f32_16x16x32_bf16(af[i], bf[j], acc[i][j], 0, 0, 0);
  }
  #pragma unroll
  for (int i = 0; i < 4; i++)
    #pragma unroll
    for (int j = 0; j < 4; j++)
      #pragma unroll
      for (int r = 0; r < 4; r++) {
        const long row = bm + wm + i * 16 + quad * 4 + r;
        const long col = bn + wn + j * 16 + l16;
        const float v = acc[i][j][r];
        if (WRITE_BF16)
          ((unsigned short*)Cout)[row * N + col] = f2bf(v);
        else
          ((float*)Cout)[row * N + col] = v;
      }
}

// ---------------- flash attention over COMPACTED keys (dynamic mask exploited) ----------------
// R11 structure unchanged (harness-verified): K/V/bias pre-compacted to keys with bias > 0,
// causal test via original-position LDS tile Is, kend ~halved.
// grid 1024 = qt(32, LPT) x b(2) x n(4) x g(4); 4 waves; wave owns 16 q rows.
// LDS: Ks 64x144 + Vs 128x72 + Ps 4x16x72 + Is 64 ints = 46,336 B -> 3 blocks/CU.
__global__ __launch_bounds__(256, 3) void k_attn(
    const unsigned short* __restrict__ qkv,   // [4096][3072] (q | k | v); q pre-scaled
    const unsigned short* __restrict__ Kc,    // [8][2048][128] compacted K (pads zero)
    const float* __restrict__ biasc,          // [8][2048] compacted bias (pads -INF)
    const unsigned short* __restrict__ vTc,   // [8][128][2048] compacted V^T (pads zero)
    const int* __restrict__ idxArr,           // [8][2048] original positions (pads INT_MAX)
    const int* __restrict__ kendArr,          // [8][32]
    const float* __restrict__ vmean,          // [1024]
    unsigned short* __restrict__ o)           // [4096][2048]
{
  int idx = blockIdx.x;
  const int g = idx & 3;
  const int n = (idx >> 2) & 3;
  const int b = (idx >> 4) & 1;
  const int qt = 31 - (idx >> 5);            // 64-row q tiles, big blocks dispatch first (LPT)
  const int tid = threadIdx.x, lane = tid & 63, wave = tid >> 6;
  const int quad = lane >> 4, l16 = lane & 15;
  const int q0 = qt * 64 + wave * 16;
  const int bn = b * 4 + n;

  __shared__ __align__(16) unsigned short Ks[64 * 144];
  __shared__ __align__(16) unsigned short Vs[128 * 72];
  __shared__ __align__(16) unsigned short Ps[4 * 16 * 72];
  __shared__ __align__(16) int Is[64];
  unsigned short* Psw = Ps + wave * 1152;    // 16 x 72 [q][key], per-wave private

  // Q fragments (B-operand for K@Q^T): row=q0+l16, k=ks*32+quad*8..+8
  short8 qf[4];
  {
    const unsigned short* qp = qkv + (long)(b * 2048) * 3072 + (n * 4 + g) * 128;
    #pragma unroll
    for (int ks = 0; ks < 4; ks++)
      qf[ks] = *reinterpret_cast<const short8*>(
          qp + (long)(q0 + l16) * 3072 + ks * 32 + quad * 8);
  }

  const floatx4 fz = {0.f, 0.f, 0.f, 0.f};
  floatx4 oacc[8];
  #pragma unroll
  for (int j = 0; j < 8; j++) oacc[j] = fz;
  float mrow = -INFINITY, lrow = 0.0f;       // per-lane: q = q0 + l16 (replicated across quads)

  const float* biasrow = biasc + bn * 2048;
  const unsigned short* kbase = Kc + (long)bn * 2048 * 128;
  const unsigned short* vbase = vTc + (long)bn * 128 * 2048;
  const int* idxp = idxArr + bn * 2048;
  const int kend = kendArr[bn * 32 + qt];
  const int kk_ = tid >> 4, hdo_ = (tid & 15) * 8;   // K staging coords (row += 16/pass)
  const int hd_ = tid >> 3, ko_ = (tid & 7) * 8;     // V staging coords (row += 32/pass)

  uintx4 kreg[4], vreg[4];
  float4 breg[4];
  int ireg;
  // prologue: load tile 0
  {
    #pragma unroll
    for (int it = 0; it < 4; it++)
      kreg[it] = *reinterpret_cast<const uintx4*>(kbase + (long)(kk_ + it * 16) * 128 + hdo_);
    #pragma unroll
    for (int it = 0; it < 4; it++)
      vreg[it] = *reinterpret_cast<const uintx4*>(vbase + (long)(hd_ + it * 32) * 2048 + ko_);
    #pragma unroll
    for (int kt = 0; kt < 4; kt++)
      breg[kt] = *reinterpret_cast<const float4*>(biasrow + kt * 16 + quad * 4);
    ireg = idxp[tid & 63];
  }

  for (int k0 = 0; k0 < kend; k0 += 64) {
    __syncthreads();  // (A) all waves done with LDS reads of previous tile
    // commit prefetched tile to LDS
    #pragma unroll
    for (int it = 0; it < 4; it++)
      *reinterpret_cast<uintx4*>(&Ks[(kk_ + it * 16) * 144 + hdo_]) = kreg[it];
    #pragma unroll
    for (int it = 0; it < 4; it++)
      *reinterpret_cast<uintx4*>(&Vs[(hd_ + it * 32) * 72 + ko_]) = vreg[it];
    if (tid < 64) Is[tid] = ireg;
    float4 bcur[4];
    #pragma unroll
    for (int kt = 0; kt < 4; kt++) bcur[kt] = breg[kt];

    // issue next tile's loads (land during this tile's compute)
    if (k0 + 64 < kend) {
      const unsigned short* kp = kbase + (long)(k0 + 64) * 128;
      const unsigned short* vp = vbase + (k0 + 64);
      #pragma unroll
      for (int it = 0; it < 4; it++)
        kreg[it] = *reinterpret_cast<const uintx4*>(kp + (long)(kk_ + it * 16) * 128 + hdo_);
      #pragma unroll
      for (int it = 0; it < 4; it++)
        vreg[it] = *reinterpret_cast<const uintx4*>(vp + (long)(hd_ + it * 32) * 2048 + ko_);
      #pragma unroll
      for (int kt = 0; kt < 4; kt++)
        breg[kt] = *reinterpret_cast<const float4*>(biasrow + (k0 + 64) + kt * 16 + quad * 4);
      ireg = idxp[k0 + 64 + (tid & 63)];
    }
    __syncthreads();  // (B) staged tile visible

    const int ifirst = Is[0];
    const bool active = (ifirst <= q0 + 15);
    if (active) {
      // S^T tile: sacc[kt] rows = compacted keys k0+kt*16+quad*4+r, col = q0+l16. C-init = bias.
      floatx4 sacc[4];
      #pragma unroll
      for (int kt = 0; kt < 4; kt++)
        sacc[kt] = (floatx4){bcur[kt].x, bcur[kt].y, bcur[kt].z, bcur[kt].w};
      __builtin_amdgcn_s_setprio(1);
      #pragma unroll
      for (int ks = 0; ks < 4; ks++) {
        short8 kf[4];
        #pragma unroll
        for (int kt = 0; kt < 4; kt++)
          kf[kt] = *reinterpret_cast<const short8*>(&Ks[(kt * 16 + l16) * 144 + ks * 32 + quad * 8]);
        #pragma unroll
        for (int kt = 0; kt < 4; kt++)
          sacc[kt] = __builtin_amdgcn_mfma_f32_16x16x32_bf16(kf[kt], qf[ks], sacc[kt], 0, 0, 0);
      }
      __builtin_amdgcn_s_setprio(0);

      // softmax (register-only): causal mask via original positions, in-lane max/sum + 2 shfls
      const int ilast = Is[63];
      const bool full = (ilast <= q0);
      if (!full) {
        const int qme = q0 + l16;
        #pragma unroll
        for (int kt = 0; kt < 4; kt++) {
          const int4 iq = *reinterpret_cast<const int4*>(&Is[kt * 16 + quad * 4]);
          if (iq.x > qme) sacc[kt][0] = -INFINITY;
          if (iq.y > qme) sacc[kt][1] = -INFINITY;
          if (iq.z > qme) sacc[kt][2] = -INFINITY;
          if (iq.w > qme) sacc[kt][3] = -INFINITY;
        }
      }
      float mx = -INFINITY;
      #pragma unroll
      for (int kt = 0; kt < 4; kt++)
        #pragma unroll
        for (int r = 0; r < 4; r++) mx = fmaxf(mx, sacc[kt][r]);
      mx = fmaxf(mx, __shfl_xor(mx, 16, 64));
      mx = fmaxf(mx, __shfl_xor(mx, 32, 64));
      const float mn = fmaxf(mrow, mx);
      const float mnc = fmaxf(mn, -1e38f);
      const float alpha = __builtin_amdgcn_exp2f(mrow - mnc);
      float rs = 0.0f;
      unsigned pk[4][2];
      #pragma unroll
      for (int kt = 0; kt < 4; kt++) {
        #pragma unroll
        for (int r = 0; r < 4; r++) {
          float p = __builtin_amdgcn_exp2f(sacc[kt][r] - mnc);
          sacc[kt][r] = p;
          rs += p;
        }
        #pragma unroll
        for (int r2 = 0; r2 < 2; r2++)
          pk[kt][r2] = (unsigned)f2bf(sacc[kt][2 * r2]) | ((unsigned)f2bf(sacc[kt][2 * r2 + 1]) << 16);
      }
      rs += __shfl_xor(rs, 16, 64);
      rs += __shfl_xor(rs, 32, 64);
      mrow = mn;
      lrow = lrow * alpha + rs;

      // rescale O: alpha in q=l16 space -> oacc q=quad*4+r space via bpermute
      float al[4];
      #pragma unroll
      for (int r = 0; r < 4; r++) al[r] = __shfl(alpha, quad * 4 + r, 64);
      #pragma unroll
      for (int j = 0; j < 8; j++)
        #pragma unroll
        for (int r = 0; r < 4; r++) oacc[j][r] *= al[r];

      // store packed P to Psw[q=l16][key] (own buffer, wave-private: no barrier)
      unsigned* Pd = reinterpret_cast<unsigned*>(Psw);
      #pragma unroll
      for (int kt = 0; kt < 4; kt++)
        #pragma unroll
        for (int r2 = 0; r2 < 2; r2++)
          Pd[l16 * 36 + kt * 8 + quad * 2 + r2] = pk[kt][r2];

      // O += P @ V  (A = P [q][key], B = V^T [key][hd])
      __builtin_amdgcn_s_setprio(1);
      #pragma unroll
      for (int ks2 = 0; ks2 < 2; ks2++) {
        short8 pf = *reinterpret_cast<const short8*>(&Psw[l16 * 72 + ks2 * 32 + quad * 8]);
        #pragma unroll
        for (int j = 0; j < 8; j++) {
          short8 vf = *reinterpret_cast<const short8*>(&Vs[(j * 16 + l16) * 72 + ks2 * 32 + quad * 8]);
          oacc[j] = __builtin_amdgcn_mfma_f32_16x16x32_bf16(pf, vf, oacc[j], 0, 0, 0);
        }
      }
      __builtin_amdgcn_s_setprio(0);
    }
  }

  // epilogue: oacc rows q=q0+quad*4+r; l lives in q=l16 space -> bpermute
  const long obase = (long)(b * 2048) * 2048 + (n * 4 + g) * 128;
  #pragma unroll
  for (int r = 0; r < 4; r++) {
    const int qrow = q0 + quad * 4 + r;
    const float l = __shfl(lrow, quad * 4 + r, 64);
    const float inv = (l > 0.0f) ? 1.0f / l : 0.0f;
    #pragma unroll
    for (int j = 0; j < 8; j++) {
      const int hd = j * 16 + l16;
      float v = oacc[j][r] * inv;
      if (l <= 0.0f) v = vmean[(b * 4 + n) * 128 + hd];  // empty row: uniform softmax over ALL keys
      o[obase + (long)qrow * 2048 + hd] = f2bf(v);
    }
  }
}

extern "C" void kernel_launch(void* const* d_in, const int* in_sizes, int n_in,
                              void* d_out, int out_size, void* d_ws, size_t ws_size,
                              hipStream_t stream) {
  const float* hs = (const float*)d_in[0];
  const float* Wq = (const float*)d_in[1];
  const float* Wk = (const float*)d_in[2];
  const float* Wv = (const float*)d_in[3];
  const float* Wg = (const float*)d_in[4];
  const float* Wd = (const float*)d_in[5];
  const float* Wo = (const float*)d_in[6];
  float* out = (float*)d_out;

  char* ws = (char*)d_ws;
  unsigned short* hsb   = (unsigned short*)(ws);               // 16,777,216 B (dead after QKV GEMM)
  unsigned short* Wcomb = (unsigned short*)(ws + 16777216);    // 12,582,912 B  [3072][2048]
  unsigned short* Wot   = (unsigned short*)(ws + 29360128);    //  8,388,608 B
  float*  Wqg   = (float*)(ws + 37748736);                     //     32,768 B
  float*  Wvd   = (float*)(ws + 37781504);                     //     32,768 B
  float*  biasb = (float*)(ws + 37814272);                     //     65,536 B
  unsigned short* qkv = (unsigned short*)(ws + 37879808);      // 25,165,824 B  [4096][3072]
  float*  vmean = (float*)(ws + 67239936);                     //      4,096 B
  unsigned short* ob  = (unsigned short*)(ws + 67244032);      // 16,777,216 B
  // compaction + vmean buffers overlay the dead hsb region (written only after the QKV GEMM):
  unsigned short* Kc    = (unsigned short*)(ws);               //  4,194,304 B [8][2048][128]
  unsigned short* vTc   = (unsigned short*)(ws + 4194304);     //  4,194,304 B [8][128][2048]
  int*   idxArr  = (int*)(ws + 8388608);                       //     65,536 B [8][2048]
  float* biascB  = (float*)(ws + 8454144);                     //     65,536 B [8][2048]
  int*   kendArr = (int*)(ws + 8519680);                       //      1,024 B [8][32]
  float* vmpart  = (float*)(ws + 8520704);                     //     65,536 B [128][128]

  const float QSCALE = 0.08838834764831845f * LOG2E;  // fold softmax scale + log2e into Q

  // 1. all weight transposes (fp32 -> bf16, B^T layout); Wq pre-scaled
  k_transpose_w_all<<<10240, 256, 0, stream>>>(Wq, Wk, Wv, Wo, Wcomb, Wot, QSCALE);

  // 2. both fused weight products
  {
    dim3 gw(2048, 2);
    k_wproj_all<<<gw, 256, 0, stream>>>(Wq, Wg, Wv, Wd, Wqg, Wvd);
  }

  // 3. bias (fp32, pre-masked + log2e-scaled) + fused hs -> bf16 conversion (single pass)
  k_bias<<<4096, 256, 0, stream>>>(hs, Wqg, Wvd, biasb, hsb);

  // 4. fused QKV projection GEMM (last reader of hsb)
  {
    dim3 gq(3072 / 128, 4096 / 128);
    k_gemm_bt<1><<<gq, 256, 0, stream>>>(hsb, Wcomb, qkv, 4096, 3072, 2048);
  }

  // 5. scan + vmean partials (one launch)
  k_scan_vmp<<<136, 256, 0, stream>>>(biasb, qkv, idxArr, biascB, kendArr, vmpart);

  // 6. K/V gathers + vmean fold (one launch)
  k_gather_all<<<3080, 256, 0, stream>>>(qkv, idxArr, Kc, vTc, vmpart, vmean);

  // 7. flash attention over compacted keys
  k_attn<<<1024, 256, 0, stream>>>(qkv, Kc, biascB, vTc, idxArr, kendArr, vmean, ob);

  // 8. output projection (fp32 out)
  {
    dim3 go(2048 / 128, 4096 / 128);
    k_gemm_bt<0><<<go, 256, 0, stream>>>(ob, Wot, out, 4096, 2048, 2048);
  }
}